// Round 7
// baseline (118.677 us; speedup 1.0000x reference)
//
#include <hip/hip_runtime.h>
#include <math.h>

#define N_ 4096
#define D_ 768
#define P_ 100
#define PPAD 128
#define NT 24                   /* K-tiles: 768 / 32 */
#define NTRI 528                /* lower-tri 128x128 tile pairs incl diag */
#define NBLK 560                /* 528 + 32 center tiles */

typedef __attribute__((ext_vector_type(8))) short short8;
typedef __attribute__((ext_vector_type(4))) float f32x4;

typedef const __attribute__((address_space(1))) void* gld_src_t;
typedef __attribute__((address_space(3))) void* gld_dst_t;
#define GLOAD16(g, d) __builtin_amdgcn_global_load_lds((gld_src_t)(g), (gld_dst_t)(d), 16, 0, 0)

#define WAITVM4() asm volatile("s_waitcnt vmcnt(4)" ::: "memory")
#define WAITVM0() asm volatile("s_waitcnt vmcnt(0)" ::: "memory")
static __device__ __forceinline__ void barrier_fenced() {
    asm volatile("" ::: "memory");
    __builtin_amdgcn_s_barrier();
    asm volatile("" ::: "memory");
}

// float -> bf16 (RNE)
__device__ inline unsigned short f2bf(float f) {
    union { float f; unsigned int u; } v; v.f = f;
    unsigned int u = v.u + 0x7fffu + ((v.u >> 16) & 1u);
    return (unsigned short)(u >> 16);
}

// ---------------------------------------------------------------------------
// tile decode shared by all mfma-style kernels.
// orig -> XCD chunk (orig%8), slot k=orig/8 (0..69). k<66: triangular tile
// from region-ordered global index g = (orig%8)*66 + k; regions are 8x8
// i-tile-group pairs so each XCD's chunk touches <=24 row-panels (L2 local).
// k>=66: center tile ci = (orig%8)*4 + (k-66), jt=32.
static __device__ __forceinline__ void decode_tile(int orig, int* pit, int* pjt) {
    const int x = orig & 7;
    const int k = orig >> 3;
    if (k >= 66) { *pit = x * 4 + (k - 66); *pjt = 32; return; }
    const int g = x * 66 + k;
    const int cumR[11] = {0, 36, 100, 136, 200, 264, 300, 364, 428, 492, 528};
    const int GIr[10] = {0, 1, 1, 2, 2, 2, 3, 3, 3, 3};
    const int GJr[10] = {0, 0, 1, 0, 1, 2, 0, 1, 2, 3};
    int r = 0;
    while (cumR[r + 1] <= g) ++r;
    const int u = g - cumR[r];
    int di, dj;
    if (GIr[r] == GJr[r]) {
        di = 0;
        while ((di + 1) * (di + 2) / 2 <= u) ++di;
        dj = u - di * (di + 1) / 2;
    } else {
        di = u >> 3; dj = u & 7;
    }
    *pit = GIr[r] * 8 + di;
    *pjt = GJr[r] * 8 + dj;
}

// ---------------------------------------------------------------------------
__global__ __launch_bounds__(256) void pre_kernel(
    const float* __restrict__ X, const float* __restrict__ C,
    float* __restrict__ sq, unsigned short* __restrict__ Xbf,
    unsigned short* __restrict__ cnbf, float* __restrict__ csq) {
    const int gw = blockIdx.x * 4 + (threadIdx.x >> 6);
    const int l = threadIdx.x & 63;
    if (gw < N_) {
        const float4* x4 = (const float4*)(X + (size_t)gw * D_);
        short4* ob = (short4*)(Xbf + (size_t)gw * D_);
        float s = 0.f;
#pragma unroll
        for (int c = 0; c < 3; ++c) {
            float4 v = x4[c * 64 + l];
            s = fmaf(v.x, v.x, fmaf(v.y, v.y, fmaf(v.z, v.z, fmaf(v.w, v.w, s))));
            short4 o;
            o.x = (short)f2bf(v.x); o.y = (short)f2bf(v.y);
            o.z = (short)f2bf(v.z); o.w = (short)f2bf(v.w);
            ob[c * 64 + l] = o;
        }
#pragma unroll
        for (int m = 1; m < 64; m <<= 1) s += __shfl_xor(s, m);
        if (l == 0) sq[gw] = s;
    } else {
        const int p = gw - N_;
        if (p >= PPAD) return;
        short4* ob = (short4*)(cnbf + (size_t)p * D_);
        if (p < P_) {
            const float4* c4 = (const float4*)(C + (size_t)p * D_);
            float4 v[3];
            float s = 0.f;
#pragma unroll
            for (int c = 0; c < 3; ++c) {
                v[c] = c4[c * 64 + l];
                s = fmaf(v[c].x, v[c].x, fmaf(v[c].y, v[c].y,
                    fmaf(v[c].z, v[c].z, fmaf(v[c].w, v[c].w, s))));
            }
#pragma unroll
            for (int m = 1; m < 64; m <<= 1) s += __shfl_xor(s, m);
            float rn = 1.0f / sqrtf(s);
#pragma unroll
            for (int c = 0; c < 3; ++c) {
                short4 o;
                o.x = (short)f2bf(v[c].x * rn); o.y = (short)f2bf(v[c].y * rn);
                o.z = (short)f2bf(v[c].z * rn); o.w = (short)f2bf(v[c].w * rn);
                ob[c * 64 + l] = o;
            }
            if (l == 0) csq[p] = s * rn * rn;
        } else {
            short4 z; z.x = z.y = z.z = z.w = 0;
#pragma unroll
            for (int c = 0; c < 3; ++c) ob[c * 64 + l] = z;
            if (l == 0) csq[p] = 1e30f;
        }
    }
}

// ===========================================================================
// Shared epilogue body (macro so probes and V0 emit identical code).
#define EPILOGUE_BODY                                                          \
    float* lf = (float*)lds;                                                   \
    __syncthreads();                                                           \
    if (!is_center) {                                                          \
        float sqj[4]; int tj[4];                                               \
        _Pragma("unroll") for (int n = 0; n < 4; ++n) {                        \
            int j = j0 + wc * 64 + n * 16 + col;                               \
            sqj[n] = sq[j]; tj[n] = T[j];                                      \
        }                                                                      \
        float apC[4], anC[4];                                                  \
        _Pragma("unroll") for (int n = 0; n < 4; ++n) { apC[n] = -1e30f; anC[n] = 1e30f; } \
        _Pragma("unroll") for (int m = 0; m < 4; ++m) {                        \
            _Pragma("unroll") for (int r = 0; r < 4; ++r) {                    \
                const int lrow = wr * 64 + m * 16 + hi * 4 + r;                \
                const int i = i0 + lrow;                                       \
                float sqi = sq[i]; int ti = T[i];                              \
                float apR = -1e30f, anR = 1e30f;                               \
                _Pragma("unroll") for (int n = 0; n < 4; ++n) {                \
                    float d2 = sqi + sqj[n] - 2.0f * acc[m][n][r];             \
                    float d = sqrtf(fmaxf(d2, 1e-12f));                        \
                    bool same = (tj[n] == ti);                                 \
                    apR = same ? fmaxf(apR, d) : apR;                          \
                    anR = same ? anR : fminf(anR, d);                          \
                    apC[n] = same ? fmaxf(apC[n], d) : apC[n];                 \
                    anC[n] = same ? anC[n] : fminf(anC[n], d);                 \
                }                                                              \
                _Pragma("unroll") for (int msk = 1; msk < 16; msk <<= 1) {     \
                    apR = fmaxf(apR, __shfl_xor(apR, msk));                    \
                    anR = fminf(anR, __shfl_xor(anR, msk));                    \
                }                                                              \
                if (col == 0) {                                                \
                    lf[wc * 128 + lrow] = apR;                                 \
                    lf[256 + wc * 128 + lrow] = anR;                           \
                }                                                              \
            }                                                                  \
        }                                                                      \
        __syncthreads();                                                       \
        if (tid < 128) {                                                       \
            float a = fmaxf(lf[tid], lf[128 + tid]);                           \
            float b = fminf(lf[256 + tid], lf[384 + tid]);                     \
            ap_part[(size_t)jt * N_ + i0 + tid] = a;                           \
            an_part[(size_t)jt * N_ + i0 + tid] = b;                           \
        }                                                                      \
        if (it != jt) {                                                        \
            __syncthreads();                                                   \
            _Pragma("unroll") for (int n = 0; n < 4; ++n) {                    \
                apC[n] = fmaxf(apC[n], __shfl_xor(apC[n], 16));                \
                apC[n] = fmaxf(apC[n], __shfl_xor(apC[n], 32));                \
                anC[n] = fminf(anC[n], __shfl_xor(anC[n], 16));                \
                anC[n] = fminf(anC[n], __shfl_xor(anC[n], 32));                \
                if (hi == 0) {                                                 \
                    int jl = wc * 64 + n * 16 + col;                           \
                    lf[wr * 128 + jl] = apC[n];                                \
                    lf[256 + wr * 128 + jl] = anC[n];                          \
                }                                                              \
            }                                                                  \
            __syncthreads();                                                   \
            if (tid < 128) {                                                   \
                float a = fmaxf(lf[tid], lf[128 + tid]);                       \
                float b = fminf(lf[256 + tid], lf[384 + tid]);                 \
                ap_part[(size_t)(32 + it) * N_ + j0 + tid] = a;                \
                an_part[(size_t)(32 + it) * N_ + j0 + tid] = b;                \
            }                                                                  \
        }                                                                      \
    } else {                                                                   \
        float sqj[4];                                                          \
        _Pragma("unroll") for (int n = 0; n < 4; ++n)                          \
            sqj[n] = csq[wc * 64 + n * 16 + col];                              \
        _Pragma("unroll") for (int m = 0; m < 4; ++m) {                        \
            _Pragma("unroll") for (int r = 0; r < 4; ++r) {                    \
                const int lrow = wr * 64 + m * 16 + hi * 4 + r;                \
                const int i = i0 + lrow;                                       \
                float sqi = sq[i];                                             \
                float mc = 1e30f;                                              \
                _Pragma("unroll") for (int n = 0; n < 4; ++n) {                \
                    float d2 = sqi + sqj[n] - 2.0f * acc[m][n][r];             \
                    float d = fmaxf(sqrtf(fmaxf(d2, 0.0f)), 1e-12f);           \
                    mc = fminf(mc, d);                                         \
                }                                                              \
                _Pragma("unroll") for (int msk = 1; msk < 16; msk <<= 1)       \
                    mc = fminf(mc, __shfl_xor(mc, msk));                       \
                if (col == 0) lf[wc * 128 + lrow] = mc;                        \
            }                                                                  \
        }                                                                      \
        __syncthreads();                                                       \
        if (tid < 128) minc[i0 + tid] = fminf(lf[tid], lf[128 + tid]);         \
    }

#define COMMON_SETUP                                                           \
    __shared__ __align__(16) unsigned short lds[3 * 8192];                     \
    const int tid = threadIdx.x;                                               \
    const int l = tid & 63;                                                    \
    const int w = tid >> 6;                                                    \
    const int wr = w >> 1;                                                     \
    const int wc = w & 1;                                                      \
    int it, jt;                                                                \
    decode_tile(blockIdx.x, &it, &jt);                                         \
    const bool is_center = (jt == 32);                                         \
    const int i0 = it * 128;                                                   \
    const int j0 = is_center ? 0 : jt * 128;                                   \
    const unsigned short* __restrict__ Bmat = is_center ? cnbf : Xbf;          \
    const int srow = tid >> 2;                                                 \
    const int scol = ((tid & 3) * 8) ^ (((srow & 6) >> 1) << 3);               \
    const unsigned short* gA0 = Xbf + (size_t)(i0 + srow) * D_ + scol;         \
    const unsigned short* gA1 = gA0 + (size_t)64 * D_;                         \
    const unsigned short* gB0 = Bmat + (size_t)(j0 + srow) * D_ + scol;        \
    const unsigned short* gB1 = gB0 + (size_t)64 * D_;                         \
    const int dA0 = w * 512, dA1 = 2048 + w * 512;                             \
    const int dB0 = 4096 + w * 512, dB1 = 6144 + w * 512;                      \
    const int col = l & 15;                                                    \
    const int hi = l >> 4;                                                     \
    const int rko = (hi * 8) ^ ((l & 6) << 2);                                 \
    const int aro = (wr * 64 + col) * 32 + rko;                                \
    const int bro = 4096 + (wc * 64 + col) * 32 + rko;                         \
    f32x4 acc[4][4];                                                           \
    _Pragma("unroll") for (int m = 0; m < 4; ++m)                              \
        _Pragma("unroll") for (int n = 0; n < 4; ++n)                          \
            acc[m][n] = (f32x4){0.f, 0.f, 0.f, 0.f};

#define STAGE(t)                                                               \
    do {                                                                       \
        const int bo_ = ((t) % 3) * 8192;                                      \
        const int ke_ = (t) * 32;                                              \
        GLOAD16(gA0 + ke_, &lds[bo_ + dA0]);                                   \
        GLOAD16(gA1 + ke_, &lds[bo_ + dA1]);                                   \
        GLOAD16(gB0 + ke_, &lds[bo_ + dB0]);                                   \
        GLOAD16(gB1 + ke_, &lds[bo_ + dB1]);                                   \
    } while (0)

#define COMPUTE_STEP(Lb)                                                       \
    do {                                                                       \
        short8 a[4], b[4];                                                     \
        _Pragma("unroll") for (int m = 0; m < 4; ++m)                          \
            a[m] = *reinterpret_cast<const short8*>((Lb) + aro + m * 512);     \
        _Pragma("unroll") for (int n = 0; n < 4; ++n)                          \
            b[n] = *reinterpret_cast<const short8*>((Lb) + bro + n * 512);     \
        _Pragma("unroll") for (int m = 0; m < 4; ++m)                          \
            _Pragma("unroll") for (int n = 0; n < 4; ++n)                      \
                acc[m][n] = __builtin_amdgcn_mfma_f32_16x16x32_bf16(           \
                    a[m], b[n], acc[m][n], 0, 0, 0);                           \
    } while (0)

// ---------------------------------------------------------------------------
// PROBE 1: no staging in loop (ring pre-filled once). Floor of the
// ds_read+MFMA+barrier loop. Outputs are garbage but fully overwritten later.
__global__ __launch_bounds__(256, 3) void probe_nostage(
    const unsigned short* __restrict__ Xbf, const unsigned short* __restrict__ cnbf,
    const int* __restrict__ T, const float* __restrict__ sq,
    const float* __restrict__ csq,
    float* __restrict__ ap_part, float* __restrict__ an_part,
    float* __restrict__ minc) {
    COMMON_SETUP
    STAGE(0); STAGE(1); STAGE(2);
    WAITVM0();
    barrier_fenced();
    int bo = 0;
    for (int t = 0; t < NT; ++t) {
        const unsigned short* Lb = &lds[bo * 8192];
        COMPUTE_STEP(Lb);
        barrier_fenced();
        bo = (bo == 2) ? 0 : bo + 1;
    }
    EPILOGUE_BODY
}

// ---------------------------------------------------------------------------
// PROBE 2: fully serial staging (stage -> vmcnt0 -> compute each step).
// Exposes raw load-completion latency per step.
__global__ __launch_bounds__(256, 3) void probe_serial(
    const unsigned short* __restrict__ Xbf, const unsigned short* __restrict__ cnbf,
    const int* __restrict__ T, const float* __restrict__ sq,
    const float* __restrict__ csq,
    float* __restrict__ ap_part, float* __restrict__ an_part,
    float* __restrict__ minc) {
    COMMON_SETUP
    int bo = 0;
    for (int t = 0; t < NT; ++t) {
        STAGE(t);
        WAITVM0();
        barrier_fenced();
        const unsigned short* Lb = &lds[bo * 8192];
        COMPUTE_STEP(Lb);
        barrier_fenced();
        bo = (bo == 2) ? 0 : bo + 1;
    }
    EPILOGUE_BODY
}

// ---------------------------------------------------------------------------
// AUTHORITATIVE kernel: R6 ring-3 counted-vmcnt structure, region-local tile
// order (decode_tile), no setprio (m190: negative on non-phase-split GEMM).
__global__ __launch_bounds__(256, 3) void mfma_kernel(
    const unsigned short* __restrict__ Xbf, const unsigned short* __restrict__ cnbf,
    const int* __restrict__ T, const float* __restrict__ sq,
    const float* __restrict__ csq,
    float* __restrict__ ap_part, float* __restrict__ an_part,
    float* __restrict__ minc) {
    COMMON_SETUP
    STAGE(0);
    STAGE(1);
    WAITVM4();
    barrier_fenced();
    int bo = 0;
    for (int t = 0; t < NT; ++t) {
        if (t + 2 < NT) STAGE(t + 2);
        const unsigned short* Lb = &lds[bo * 8192];
        COMPUTE_STEP(Lb);
        if (t < NT - 1) {
            if (t + 2 < NT) WAITVM4();
            else WAITVM0();
            barrier_fenced();
        }
        bo = (bo == 2) ? 0 : bo + 1;
    }
    EPILOGUE_BODY
}

// ---------------------------------------------------------------------------
__global__ __launch_bounds__(256) void combine1(
    const float* __restrict__ ap_part, const float* __restrict__ an_part,
    const float* __restrict__ minc, float* __restrict__ bsum) {
    __shared__ float sred[4];
    const int i = blockIdx.x * 256 + threadIdx.x;
    const int r = i >> 7;
    float ap = -1e30f, an = 1e30f;
    for (int jt = 0; jt <= r; ++jt) {
        ap = fmaxf(ap, ap_part[(size_t)jt * N_ + i]);
        an = fminf(an, an_part[(size_t)jt * N_ + i]);
    }
    for (int it2 = r + 1; it2 < 32; ++it2) {
        ap = fmaxf(ap, ap_part[(size_t)(32 + it2) * N_ + i]);
        an = fminf(an, an_part[(size_t)(32 + it2) * N_ + i]);
    }
    float dan = (an < 1e29f) ? an : (ap + 1.0f);
    dan = fminf(dan, minc[i]);
    float term = fmaxf(0.0f, 1.0f + ap - dan);
#pragma unroll
    for (int m = 32; m > 0; m >>= 1) term += __shfl_xor(term, m);
    if ((threadIdx.x & 63) == 0) sred[threadIdx.x >> 6] = term;
    __syncthreads();
    if (threadIdx.x == 0)
        bsum[blockIdx.x] = sred[0] + sred[1] + sred[2] + sred[3];
}

__global__ void finalize(const float* __restrict__ bsum, float* __restrict__ out) {
    if (threadIdx.x == 0) {
        float s = 0.f;
        for (int b = 0; b < N_ / 256; ++b) s += bsum[b];
        out[0] = s / (float)N_;
    }
}

// ---------------------------------------------------------------------------
// Workspace layout (floats; audited, same as R6):
//   sq      : [0,        4096)
//   csq     : [4096,     4224)
//   minc    : [4224,     8320)
//   bsum    : [8320,     8336)
//   Xbf     : [8336,     1581200)   4096*768 ushorts = 1,572,864 floats
//   cnbf    : [1581200,  1630352)   128*768 ushorts  =    49,152 floats
//   ap_part : [1630352,  1892496)   64*4096 floats
//   an_part : [1892496,  2154640)   64*4096 floats   (~8.62 MB total)
extern "C" void kernel_launch(void* const* d_in, const int* in_sizes, int n_in,
                              void* d_out, int out_size, void* d_ws, size_t ws_size,
                              hipStream_t stream) {
    const float* X = (const float*)d_in[0];
    const int* T = (const int*)d_in[1];
    const float* C = (const float*)d_in[2];
    float* out = (float*)d_out;

    float* ws = (float*)d_ws;
    float* sq = ws;
    float* csq = ws + 4096;
    float* minc = ws + 4224;
    float* bsum = ws + 8320;
    unsigned short* Xbf = (unsigned short*)(ws + 8336);
    unsigned short* cnbf = (unsigned short*)(ws + 1581200);
    float* ap_part = ws + 1630352;
    float* an_part = ws + 1892496;

    pre_kernel<<<(N_ + PPAD) / 4, 256, 0, stream>>>(X, C, sq, Xbf, cnbf, csq);
    // diagnostic probes (garbage outputs, deterministically overwritten below)
    probe_nostage<<<NBLK, 256, 0, stream>>>(Xbf, cnbf, T, sq, csq, ap_part, an_part, minc);
    probe_serial<<<NBLK, 256, 0, stream>>>(Xbf, cnbf, T, sq, csq, ap_part, an_part, minc);
    // authoritative
    mfma_kernel<<<NBLK, 256, 0, stream>>>(Xbf, cnbf, T, sq, csq, ap_part, an_part, minc);
    combine1<<<N_ / 256, 256, 0, stream>>>(ap_part, an_part, minc, bsum);
    finalize<<<1, 64, 0, stream>>>(bsum, out);
}

// Round 8
// 67.394 us; speedup vs baseline: 1.7610x; 1.7610x over previous
//
#include <hip/hip_runtime.h>
#include <math.h>

#define N_ 4096
#define D_ 768
#define P_ 100
#define PPAD 128
#define NT64 12                 /* K-steps: 768 / 64 */
#define NTRI 528                /* lower-tri 128x128 tile pairs incl diag */
#define NBLK 560                /* 528 + 32 center tiles */

typedef __attribute__((ext_vector_type(8))) short short8;
typedef __attribute__((ext_vector_type(4))) float f32x4;

typedef const __attribute__((address_space(1))) void* gld_src_t;
typedef __attribute__((address_space(3))) void* gld_dst_t;
#define GLOAD16(g, d) __builtin_amdgcn_global_load_lds((gld_src_t)(g), (gld_dst_t)(d), 16, 0, 0)

#define WAITVM0() asm volatile("s_waitcnt vmcnt(0)" ::: "memory")
static __device__ __forceinline__ void barrier_fenced() {
    asm volatile("" ::: "memory");
    __builtin_amdgcn_s_barrier();
    asm volatile("" ::: "memory");
}

// float -> bf16 (RNE)
__device__ inline unsigned short f2bf(float f) {
    union { float f; unsigned int u; } v; v.f = f;
    unsigned int u = v.u + 0x7fffu + ((v.u >> 16) & 1u);
    return (unsigned short)(u >> 16);
}

// ---------------------------------------------------------------------------
// tile decode: orig -> XCD chunk (orig%8), slot k (0..69). k<66: triangular
// tile from region-ordered index (8-i-tile-group regions, L2-local per XCD);
// k>=66: center tile.
static __device__ __forceinline__ void decode_tile(int orig, int* pit, int* pjt) {
    const int x = orig & 7;
    const int k = orig >> 3;
    if (k >= 66) { *pit = x * 4 + (k - 66); *pjt = 32; return; }
    const int g = x * 66 + k;
    const int cumR[11] = {0, 36, 100, 136, 200, 264, 300, 364, 428, 492, 528};
    const int GIr[10] = {0, 1, 1, 2, 2, 2, 3, 3, 3, 3};
    const int GJr[10] = {0, 0, 1, 0, 1, 2, 0, 1, 2, 3};
    int r = 0;
    while (cumR[r + 1] <= g) ++r;
    const int u = g - cumR[r];
    int di, dj;
    if (GIr[r] == GJr[r]) {
        di = 0;
        while ((di + 1) * (di + 2) / 2 <= u) ++di;
        dj = u - di * (di + 1) / 2;
    } else {
        di = u >> 3; dj = u & 7;
    }
    *pit = GIr[r] * 8 + di;
    *pjt = GJr[r] * 8 + dj;
}

// ---------------------------------------------------------------------------
__global__ __launch_bounds__(256) void pre_kernel(
    const float* __restrict__ X, const float* __restrict__ C,
    float* __restrict__ sq, unsigned short* __restrict__ Xbf,
    unsigned short* __restrict__ cnbf, float* __restrict__ csq) {
    const int gw = blockIdx.x * 4 + (threadIdx.x >> 6);
    const int l = threadIdx.x & 63;
    if (gw < N_) {
        const float4* x4 = (const float4*)(X + (size_t)gw * D_);
        short4* ob = (short4*)(Xbf + (size_t)gw * D_);
        float s = 0.f;
#pragma unroll
        for (int c = 0; c < 3; ++c) {
            float4 v = x4[c * 64 + l];
            s = fmaf(v.x, v.x, fmaf(v.y, v.y, fmaf(v.z, v.z, fmaf(v.w, v.w, s))));
            short4 o;
            o.x = (short)f2bf(v.x); o.y = (short)f2bf(v.y);
            o.z = (short)f2bf(v.z); o.w = (short)f2bf(v.w);
            ob[c * 64 + l] = o;
        }
#pragma unroll
        for (int m = 1; m < 64; m <<= 1) s += __shfl_xor(s, m);
        if (l == 0) sq[gw] = s;
    } else {
        const int p = gw - N_;
        if (p >= PPAD) return;
        short4* ob = (short4*)(cnbf + (size_t)p * D_);
        if (p < P_) {
            const float4* c4 = (const float4*)(C + (size_t)p * D_);
            float4 v[3];
            float s = 0.f;
#pragma unroll
            for (int c = 0; c < 3; ++c) {
                v[c] = c4[c * 64 + l];
                s = fmaf(v[c].x, v[c].x, fmaf(v[c].y, v[c].y,
                    fmaf(v[c].z, v[c].z, fmaf(v[c].w, v[c].w, s))));
            }
#pragma unroll
            for (int m = 1; m < 64; m <<= 1) s += __shfl_xor(s, m);
            float rn = 1.0f / sqrtf(s);
#pragma unroll
            for (int c = 0; c < 3; ++c) {
                short4 o;
                o.x = (short)f2bf(v[c].x * rn); o.y = (short)f2bf(v[c].y * rn);
                o.z = (short)f2bf(v[c].z * rn); o.w = (short)f2bf(v[c].w * rn);
                ob[c * 64 + l] = o;
            }
            if (l == 0) csq[p] = s * rn * rn;
        } else {
            short4 z; z.x = z.y = z.z = z.w = 0;
#pragma unroll
            for (int c = 0; c < 3; ++c) ob[c * 64 + l] = z;
            if (l == 0) csq[p] = 1e30f;
        }
    }
}

// ---------------------------------------------------------------------------
// MFMA kernel: 128x128 tile, BK=64, double-buffered 64 KB LDS, ONE barrier
// per K-step (12 total). Zero-conflict XOR-swizzled LDS (verified). Symmetric
// lower-tri tiles; off-diag tiles fold row-side AND col-side reductions.
// Slots: row-side jt (0..31); col-side 32+it (33..63); centers -> minc.
__global__ __launch_bounds__(256, 2) void mfma_kernel(
    const unsigned short* __restrict__ Xbf, const unsigned short* __restrict__ cnbf,
    const int* __restrict__ T, const float* __restrict__ sq,
    const float* __restrict__ csq,
    float* __restrict__ ap_part, float* __restrict__ an_part,
    float* __restrict__ minc) {
    // 2 buffers x 2 k-chunks x (A 4096 us | B 4096 us) = 64 KB
    __shared__ __align__(16) unsigned short lds[2 * 16384];

    const int tid = threadIdx.x;
    const int l = tid & 63;
    const int w = tid >> 6;       // wave 0..3
    const int wr = w >> 1;        // wave row (0/1)
    const int wc = w & 1;         // wave col (0/1)

    int it, jt;
    decode_tile(blockIdx.x, &it, &jt);
    const bool is_center = (jt == 32);
    const int i0 = it * 128;
    const int j0 = is_center ? 0 : jt * 128;
    const unsigned short* __restrict__ Bmat = is_center ? cnbf : Xbf;

    // ---- staging addressing (verified zero-conflict pattern) ----
    const int srow = tid >> 2;                                  // 0..63
    const int scol = ((tid & 3) * 8) ^ (((srow & 6) >> 1) << 3);
    const unsigned short* gA0 = Xbf + (size_t)(i0 + srow) * D_ + scol;
    const unsigned short* gA1 = gA0 + (size_t)64 * D_;
    const unsigned short* gB0 = Bmat + (size_t)(j0 + srow) * D_ + scol;
    const unsigned short* gB1 = gB0 + (size_t)64 * D_;
    const int dA0 = w * 512, dA1 = 2048 + w * 512;
    const int dB0 = 4096 + w * 512, dB1 = 6144 + w * 512;

    // ---- fragment read addressing (swizzled, matches stage flip) ----
    const int col = l & 15;
    const int hi = l >> 4;
    const int rko = (hi * 8) ^ ((l & 6) << 2);
    const int aro = (wr * 64 + col) * 32 + rko;
    const int bro = 4096 + (wc * 64 + col) * 32 + rko;

    f32x4 acc[4][4];
#pragma unroll
    for (int m = 0; m < 4; ++m)
#pragma unroll
        for (int n = 0; n < 4; ++n) acc[m][n] = (f32x4){0.f, 0.f, 0.f, 0.f};

    // stage one BK=64 step (two 32-k chunks) into buffer p
#define STAGE64(t, p)                                                  \
    do {                                                               \
        unsigned short* db_ = &lds[(p) * 16384];                       \
        const int ke_ = (t) * 64;                                      \
        GLOAD16(gA0 + ke_, db_ + dA0);                                 \
        GLOAD16(gA1 + ke_, db_ + dA1);                                 \
        GLOAD16(gB0 + ke_, db_ + dB0);                                 \
        GLOAD16(gB1 + ke_, db_ + dB1);                                 \
        GLOAD16(gA0 + ke_ + 32, db_ + 8192 + dA0);                     \
        GLOAD16(gA1 + ke_ + 32, db_ + 8192 + dA1);                     \
        GLOAD16(gB0 + ke_ + 32, db_ + 8192 + dB0);                     \
        GLOAD16(gB1 + ke_ + 32, db_ + 8192 + dB1);                     \
    } while (0)

    STAGE64(0, 0);
    WAITVM0();
    barrier_fenced();

    int p = 0;
    for (int t = 0; t < NT64; ++t) {
        if (t + 1 < NT64) STAGE64(t + 1, p ^ 1);   // issue early, lands during compute
        const unsigned short* Lb = &lds[p * 16384];
#pragma unroll
        for (int c = 0; c < 2; ++c) {
            short8 a[4], b[4];
#pragma unroll
            for (int m = 0; m < 4; ++m)
                a[m] = *reinterpret_cast<const short8*>(Lb + c * 8192 + aro + m * 512);
#pragma unroll
            for (int n = 0; n < 4; ++n)
                b[n] = *reinterpret_cast<const short8*>(Lb + c * 8192 + bro + n * 512);
#pragma unroll
            for (int m = 0; m < 4; ++m)
#pragma unroll
                for (int n = 0; n < 4; ++n)
                    acc[m][n] = __builtin_amdgcn_mfma_f32_16x16x32_bf16(
                        a[m], b[n], acc[m][n], 0, 0, 0);
        }
        WAITVM0();          // next buffer's loads had the whole compute to land
        barrier_fenced();   // also: everyone done reading buf p before restage
        p ^= 1;
    }
#undef STAGE64

    // ---------------- epilogue -------------------------------------------
    // C/D layout: col = lane&15, row = (lane>>4)*4 + reg
    float* lf = (float*)lds;
    __syncthreads();

    if (!is_center) {
        float sqj[4]; int tj[4];
#pragma unroll
        for (int n = 0; n < 4; ++n) {
            int j = j0 + wc * 64 + n * 16 + col;
            sqj[n] = sq[j];
            tj[n] = T[j];
        }
        float apC[4], anC[4];
#pragma unroll
        for (int n = 0; n < 4; ++n) { apC[n] = -1e30f; anC[n] = 1e30f; }

#pragma unroll
        for (int m = 0; m < 4; ++m) {
#pragma unroll
            for (int r = 0; r < 4; ++r) {
                const int lrow = wr * 64 + m * 16 + hi * 4 + r;   // 0..127
                const int i = i0 + lrow;
                float sqi = sq[i];
                int ti = T[i];
                float apR = -1e30f, anR = 1e30f;
#pragma unroll
                for (int n = 0; n < 4; ++n) {
                    float d2 = sqi + sqj[n] - 2.0f * acc[m][n][r];
                    float d = sqrtf(fmaxf(d2, 1e-12f));
                    bool same = (tj[n] == ti);
                    apR = same ? fmaxf(apR, d) : apR;
                    anR = same ? anR : fminf(anR, d);
                    apC[n] = same ? fmaxf(apC[n], d) : apC[n];
                    anC[n] = same ? anC[n] : fminf(anC[n], d);
                }
#pragma unroll
                for (int msk = 1; msk < 16; msk <<= 1) {
                    apR = fmaxf(apR, __shfl_xor(apR, msk));
                    anR = fminf(anR, __shfl_xor(anR, msk));
                }
                if (col == 0) {
                    lf[wc * 128 + lrow] = apR;
                    lf[256 + wc * 128 + lrow] = anR;
                }
            }
        }
        __syncthreads();
        if (tid < 128) {
            float a = fmaxf(lf[tid], lf[128 + tid]);
            float b = fminf(lf[256 + tid], lf[384 + tid]);
            ap_part[(size_t)jt * N_ + i0 + tid] = a;
            an_part[(size_t)jt * N_ + i0 + tid] = b;
        }

        if (it != jt) {
            __syncthreads();
#pragma unroll
            for (int n = 0; n < 4; ++n) {
                apC[n] = fmaxf(apC[n], __shfl_xor(apC[n], 16));
                apC[n] = fmaxf(apC[n], __shfl_xor(apC[n], 32));
                anC[n] = fminf(anC[n], __shfl_xor(anC[n], 16));
                anC[n] = fminf(anC[n], __shfl_xor(anC[n], 32));
                if (hi == 0) {
                    int jl = wc * 64 + n * 16 + col;            // 0..127
                    lf[wr * 128 + jl] = apC[n];
                    lf[256 + wr * 128 + jl] = anC[n];
                }
            }
            __syncthreads();
            if (tid < 128) {
                float a = fmaxf(lf[tid], lf[128 + tid]);
                float b = fminf(lf[256 + tid], lf[384 + tid]);
                ap_part[(size_t)(32 + it) * N_ + j0 + tid] = a;
                an_part[(size_t)(32 + it) * N_ + j0 + tid] = b;
            }
        }
    } else {
        float sqj[4];
#pragma unroll
        for (int n = 0; n < 4; ++n) sqj[n] = csq[wc * 64 + n * 16 + col];
#pragma unroll
        for (int m = 0; m < 4; ++m) {
#pragma unroll
            for (int r = 0; r < 4; ++r) {
                const int lrow = wr * 64 + m * 16 + hi * 4 + r;
                const int i = i0 + lrow;
                float sqi = sq[i];
                float mc = 1e30f;
#pragma unroll
                for (int n = 0; n < 4; ++n) {
                    float d2 = sqi + sqj[n] - 2.0f * acc[m][n][r];
                    float d = fmaxf(sqrtf(fmaxf(d2, 0.0f)), 1e-12f);
                    mc = fminf(mc, d);
                }
#pragma unroll
                for (int msk = 1; msk < 16; msk <<= 1)
                    mc = fminf(mc, __shfl_xor(mc, msk));
                if (col == 0) lf[wc * 128 + lrow] = mc;
            }
        }
        __syncthreads();
        if (tid < 128) minc[i0 + tid] = fminf(lf[tid], lf[128 + tid]);
    }
}

// ---------------------------------------------------------------------------
__global__ __launch_bounds__(256) void combine1(
    const float* __restrict__ ap_part, const float* __restrict__ an_part,
    const float* __restrict__ minc, float* __restrict__ bsum) {
    __shared__ float sred[4];
    const int i = blockIdx.x * 256 + threadIdx.x;
    const int r = i >> 7;
    float ap = -1e30f, an = 1e30f;
    for (int jt = 0; jt <= r; ++jt) {
        ap = fmaxf(ap, ap_part[(size_t)jt * N_ + i]);
        an = fminf(an, an_part[(size_t)jt * N_ + i]);
    }
    for (int it2 = r + 1; it2 < 32; ++it2) {
        ap = fmaxf(ap, ap_part[(size_t)(32 + it2) * N_ + i]);
        an = fminf(an, an_part[(size_t)(32 + it2) * N_ + i]);
    }
    float dan = (an < 1e29f) ? an : (ap + 1.0f);
    dan = fminf(dan, minc[i]);
    float term = fmaxf(0.0f, 1.0f + ap - dan);
#pragma unroll
    for (int m = 32; m > 0; m >>= 1) term += __shfl_xor(term, m);
    if ((threadIdx.x & 63) == 0) sred[threadIdx.x >> 6] = term;
    __syncthreads();
    if (threadIdx.x == 0)
        bsum[blockIdx.x] = sred[0] + sred[1] + sred[2] + sred[3];
}

__global__ void finalize(const float* __restrict__ bsum, float* __restrict__ out) {
    if (threadIdx.x == 0) {
        float s = 0.f;
        for (int b = 0; b < N_ / 256; ++b) s += bsum[b];
        out[0] = s / (float)N_;
    }
}

// ---------------------------------------------------------------------------
// Workspace layout (floats; audited, same as R6/R7):
//   sq      : [0,        4096)
//   csq     : [4096,     4224)
//   minc    : [4224,     8320)
//   bsum    : [8320,     8336)
//   Xbf     : [8336,     1581200)   4096*768 ushorts = 1,572,864 floats
//   cnbf    : [1581200,  1630352)   128*768 ushorts  =    49,152 floats
//   ap_part : [1630352,  1892496)   64*4096 floats
//   an_part : [1892496,  2154640)   64*4096 floats   (~8.62 MB total)
extern "C" void kernel_launch(void* const* d_in, const int* in_sizes, int n_in,
                              void* d_out, int out_size, void* d_ws, size_t ws_size,
                              hipStream_t stream) {
    const float* X = (const float*)d_in[0];
    const int* T = (const int*)d_in[1];
    const float* C = (const float*)d_in[2];
    float* out = (float*)d_out;

    float* ws = (float*)d_ws;
    float* sq = ws;
    float* csq = ws + 4096;
    float* minc = ws + 4224;
    float* bsum = ws + 8320;
    unsigned short* Xbf = (unsigned short*)(ws + 8336);
    unsigned short* cnbf = (unsigned short*)(ws + 1581200);
    float* ap_part = ws + 1630352;
    float* an_part = ws + 1892496;

    pre_kernel<<<(N_ + PPAD) / 4, 256, 0, stream>>>(X, C, sq, Xbf, cnbf, csq);
    mfma_kernel<<<NBLK, 256, 0, stream>>>(Xbf, cnbf, T, sq, csq, ap_part, an_part, minc);
    combine1<<<N_ / 256, 256, 0, stream>>>(ap_part, an_part, minc, bsum);
    finalize<<<1, 64, 0, stream>>>(bsum, out);
}